// Round 11
// baseline (143.117 us; speedup 1.0000x reference)
//
#include <hip/hip_runtime.h>
#include <math.h>

#define NSITES 100000
#define NYEARS 20
#define HDIM 64
#define WSTR 72   // LDS weight row stride (f16 elems); 144B, 16B-aligned

typedef _Float16 f16x8 __attribute__((ext_vector_type(8)));
typedef _Float16 hx2   __attribute__((ext_vector_type(2)));
typedef float f32x4 __attribute__((ext_vector_type(4)));

__device__ __forceinline__ float sigmoidf_(float x) { return 1.0f / (1.0f + __expf(-x)); }
__device__ __forceinline__ float eluf_(float x) { return x > 0.0f ? x : __expf(x) - 1.0f; }

__device__ __forceinline__ unsigned short h16_(float a) {
    union { _Float16 h; unsigned short u; } x; x.h = (_Float16)a; return x.u;
}
__device__ __forceinline__ unsigned pack2h_(float a, float b) {
    return ((unsigned)h16_(b) << 16) | (unsigned)h16_(a);
}

// load 8 consecutive f32 (32B-aligned) -> f16x8
__device__ __forceinline__ f16x8 cvt8h_(const float* p) {
    float4 a = ((const float4*)p)[0];
    float4 b = ((const float4*)p)[1];
    f16x8 r;
    r[0] = (_Float16)a.x; r[1] = (_Float16)a.y; r[2] = (_Float16)a.z; r[3] = (_Float16)a.w;
    r[4] = (_Float16)b.x; r[5] = (_Float16)b.y; r[6] = (_Float16)b.z; r[7] = (_Float16)b.w;
    return r;
}

// 16B LDS read at laundered byte offset + compile-time immediate
__device__ __forceinline__ f16x8 ldsb_(const char* base, unsigned boff, int imm) {
    union { f16x8 v; uint4 u; } r;
    r.u = *(const uint4*)(base + boff + imm);
    return r.v;
}

union FragU { hx2 h2[4]; f16x8 v; };

// R23: the 8-waves/SIMD experiment, done right. R12-R22 evidence: dur is
// residency(4 waves/SIMD, VGPR bucket 65-128) x per-wave issue density (~11%,
// latency-bound serial chain) ~= 44us invariant. The untested cell: VGPR<=64
// -> 8 waves/SIMD. Previous caps (R14/R17/R21) spilled because live state
// wasn't reduced. This round REMOVES the state:
//  - a_hh (32 VGPR) + a_head (8) -> per-iteration LDS reads from whh_l
//    (10 ds_read_b128/iter, base+imm offsets; asm-laundered offset defeats
//    LICM re-hoisting). LDS-BW floor ~16us, below target.
//  - biasD f32 C-operand (16) -> packed-f16 bias2 (8) + zero-C MFMA init.
//  - head biases (b_psi/b_p/b_psi0) -> uniform scalar loads, added at the
//    q==0 write (headC eliminated).
// Persistent loop state ~34 VGPR, peak ~60-66: launch_bounds(256,8) cap=64
// is feasible. LDS: whh_l 68 rows (64 W_hh + W_psi/W_p/W_psi0) = 9792B +
// logits 10240B = 20032B -> 8 blocks/CU = 160.3KB of 160KB.
// VALIDITY GATE: WRITE_SIZE < 28MB (spill check). wh1 read direct from
// global in h0 (R22-validated). Loop = validated R8/R10 permuted-output-row
// recurrence; slot semantics: pL[sl*20+k]=p-logit(h_k) k=0..19;
// psiL[sl*20+k]=psi-logit(h_k) k=1..19, slot0 = psi0-logit.
__global__ __launch_bounds__(256, 8)
void rnet_kernel(const float* __restrict__ sxy0,
                 const float* __restrict__ sxy,
                 const float* __restrict__ oxy,
                 const float* __restrict__ W_h0, const float* __restrict__ b_h0,
                 const float* __restrict__ W_h1, const float* __restrict__ b_h1,
                 const float* __restrict__ W_ih, const float* __restrict__ b_ih,
                 const float* __restrict__ W_hh, const float* __restrict__ b_hh,
                 const float* __restrict__ W_psi0, const float* __restrict__ b_psi0,
                 const float* __restrict__ W_psi, const float* __restrict__ b_psi,
                 const float* __restrict__ W_p, const float* __restrict__ b_p,
                 float* __restrict__ out)
{
    const int tid  = threadIdx.x;       // 0..255
    const int lane = tid & 63;
    const int wv   = tid >> 6;          // wave 0..3
    const int s = lane & 15;            // site within wave / A-row within tile
    const int q = lane >> 4;            // quad
    const int sq = s >> 2, sr = s & 3;
    const int base = blockIdx.x * 64;   // 1563 blocks; last block partial
    const int sl   = wv * 16 + s;       // site local 0..63
    const int site = base + sl;
    const int site_ld = site < NSITES ? site : NSITES - 1;

    __shared__ __align__(16) unsigned short whh_l[68 * WSTR]; // 9792B: W_hh + 3 head rows
    __shared__ __align__(16) float pL[64 * 20];               // 5120B p-logits
    __shared__ __align__(16) float psiL[64 * 20];             // 5120B psi-logits; slot0=psi0

    float* __restrict__ out_psi0 = out;                 // [N]
    float* __restrict__ out_psi  = out + NSITES;        // [N,19]
    float* __restrict__ out_p    = out + 20 * NSITES;   // [N,20,2]

    // ==== stage W_hh (rows 0..63) + head rows (64..66) into LDS ====
    {
        const float4* whg = (const float4*)W_hh;
#pragma unroll
        for (int j = 0; j < 4; ++j) {
            int e4 = j * 256 + tid;            // 0..1023
            int row = e4 >> 4, c4 = e4 & 15;
            float4 a = whg[e4];
            uint2 pa; pa.x = pack2h_(a.x, a.y); pa.y = pack2h_(a.z, a.w);
            *(uint2*)&whh_l[row * WSTR + c4 * 4] = pa;
        }
        if (tid < 192) {
            int r = tid >> 6, c = tid & 63;
            const float* src = (r == 0) ? W_psi : ((r == 1) ? W_p : W_psi0);
            whh_l[(64 + r) * WSTR + c] = h16_(src[c]);
        }
    }
    __syncthreads();

    // ==== h0 stage: hs = elu(s0*W_h0+b_h0); h0 via W_h1 DIRECT from global ====
    f16x8 bf[2];
    {
        const float s0v = sxy0[site_ld];
        f16x8 bf0[2];
#pragma unroll
        for (int kt = 0; kt < 2; ++kt) {
            const float* wp = W_h0 + kt * 32 + q * 8;
            const float* bp = b_h0 + kt * 32 + q * 8;
            float4 w0 = ((const float4*)wp)[0], w1 = ((const float4*)wp)[1];
            float4 c0 = ((const float4*)bp)[0], c1 = ((const float4*)bp)[1];
            float v[8];
            v[0] = eluf_(fmaf(s0v, w0.x, c0.x)); v[1] = eluf_(fmaf(s0v, w0.y, c0.y));
            v[2] = eluf_(fmaf(s0v, w0.z, c0.z)); v[3] = eluf_(fmaf(s0v, w0.w, c0.w));
            v[4] = eluf_(fmaf(s0v, w1.x, c1.x)); v[5] = eluf_(fmaf(s0v, w1.y, c1.y));
            v[6] = eluf_(fmaf(s0v, w1.z, c1.z)); v[7] = eluf_(fmaf(s0v, w1.w, c1.w));
#pragma unroll
            for (int j = 0; j < 8; ++j) bf0[kt][j] = (_Float16)v[j];
        }

        f32x4 acc[4];
#pragma unroll
        for (int mt = 0; mt < 4; ++mt) {
            const int dr = 32 * (mt >> 1) + 8 * q + 4 * (mt & 1);
            float4 b1 = *(const float4*)(b_h1 + dr);
            acc[mt][0] = b1.x; acc[mt][1] = b1.y; acc[mt][2] = b1.z; acc[mt][3] = b1.w;
        }
#pragma unroll
        for (int kt = 0; kt < 2; ++kt)
#pragma unroll
            for (int mt = 0; mt < 4; ++mt) {
                const int ar = 32 * (mt >> 1) + 8 * sq + 4 * (mt & 1) + sr;
                f16x8 a = cvt8h_(W_h1 + ar * HDIM + kt * 32 + q * 8);
                acc[mt] = __builtin_amdgcn_mfma_f32_16x16x32_f16(a, bf0[kt], acc[mt], 0, 0, 0);
            }
        FragU f0, f1;
#pragma unroll
        for (int mt = 0; mt < 4; ++mt) {
            hx2 plo; plo[0] = (_Float16)eluf_(acc[mt][0]); plo[1] = (_Float16)eluf_(acc[mt][1]);
            hx2 phi; phi[0] = (_Float16)eluf_(acc[mt][2]); phi[1] = (_Float16)eluf_(acc[mt][3]);
            if (mt < 2) { f0.h2[mt * 2] = plo; f0.h2[mt * 2 + 1] = phi; }
            else        { f1.h2[(mt - 2) * 2] = plo; f1.h2[(mt - 2) * 2 + 1] = phi; }
        }
        bf[0] = f0.v;
        bf[1] = f1.v;
    }

    // ==== minimal persistent loop state ====
    const int hsel = (s == 1) ? 1 : ((s == 2) ? 2 : 0);
    unsigned ahh_off = (unsigned)(((8 * sq + sr) * WSTR + q * 8) * 2);   // byte, 16B-aligned
    unsigned ahd_off = (unsigned)(((64 + hsel) * WSTR + q * 8) * 2);
    hx2 wih2[4][2], bias2[4][2];
#pragma unroll
    for (int mt = 0; mt < 4; ++mt) {
        const int dr = 32 * (mt >> 1) + 8 * q + 4 * (mt & 1);
        float4 bi = *(const float4*)(b_ih + dr);
        float4 bh = *(const float4*)(b_hh + dr);
        float4 wi = *(const float4*)(W_ih + dr);
        bias2[mt][0][0] = (_Float16)(bi.x + bh.x); bias2[mt][0][1] = (_Float16)(bi.y + bh.y);
        bias2[mt][1][0] = (_Float16)(bi.z + bh.z); bias2[mt][1][1] = (_Float16)(bi.w + bh.w);
        wih2[mt][0][0] = (_Float16)wi.x; wih2[mt][0][1] = (_Float16)wi.y;
        wih2[mt][1][0] = (_Float16)wi.z; wih2[mt][1][1] = (_Float16)wi.w;
    }
    const float bpsiS  = b_psi[0];    // uniform -> SGPR
    const float bpS    = b_p[0];
    const float bpsi0S = b_psi0[0];
    f32x4 zc; zc[0] = 0.0f; zc[1] = 0.0f; zc[2] = 0.0f; zc[3] = 0.0f;
    const hx2 z2 = (hx2)(_Float16)0.0f;
    const float* __restrict__ xs_g = sxy + (size_t)site_ld * 19;
    const char* wb = (const char*)whh_l;
    // frag byte offsets: OFF(mt,kt) = (32*(mt>>1)+4*(mt&1))*144 + kt*64
#define OFFH(mt, kt) ((32 * ((mt) >> 1) + 4 * ((mt) & 1)) * 144 + (kt) * 64)

    // ==== recurrence: ROLLED; a_hh/a_head re-read from LDS each iteration ====
    float x = xs_g[0];
#pragma unroll 1
    for (int t = 1; t < NYEARS; ++t) {
        float x_next = (t < NYEARS - 1) ? xs_g[t] : 0.0f;
        // launder offsets so LICM can't hoist the (loop-invariant) LDS reads
        asm volatile("" : "+v"(ahh_off), "+v"(ahd_off));

        f32x4 acc[4], accH;
#pragma unroll
        for (int mt = 0; mt < 4; ++mt)
            acc[mt] = __builtin_amdgcn_mfma_f32_16x16x32_f16(ldsb_(wb, ahh_off, OFFH(mt, 0)), bf[0], zc, 0, 0, 0);
        accH = __builtin_amdgcn_mfma_f32_16x16x32_f16(ldsb_(wb, ahd_off, 0), bf[0], zc, 0, 0, 0);
#pragma unroll
        for (int mt = 0; mt < 4; ++mt)
            acc[mt] = __builtin_amdgcn_mfma_f32_16x16x32_f16(ldsb_(wb, ahh_off, OFFH(mt, 1)), bf[1], acc[mt], 0, 0, 0);
        accH = __builtin_amdgcn_mfma_f32_16x16x32_f16(ldsb_(wb, ahd_off, 64), bf[1], accH, 0, 0, 0);

        // packed-f16 update: hn = max(cvt(acc) + (x*wih + bias), 0)
        _Float16 xh = (_Float16)x;
        hx2 x2; x2[0] = xh; x2[1] = xh;
        FragU f0, f1;
#pragma unroll
        for (int mt = 0; mt < 4; ++mt) {
            hx2 xlo = x2 * wih2[mt][0] + bias2[mt][0];
            hx2 xhi = x2 * wih2[mt][1] + bias2[mt][1];
            hx2 plo; plo[0] = (_Float16)acc[mt][0]; plo[1] = (_Float16)acc[mt][1];
            hx2 phi; phi[0] = (_Float16)acc[mt][2]; phi[1] = (_Float16)acc[mt][3];
            plo = __builtin_elementwise_max(plo + xlo, z2);
            phi = __builtin_elementwise_max(phi + xhi, z2);
            if (mt < 2) { f0.h2[mt * 2] = plo; f0.h2[mt * 2 + 1] = phi; }
            else        { f1.h2[(mt - 2) * 2] = plo; f1.h2[(mt - 2) * 2 + 1] = phi; }
        }
        bf[0] = f0.v;
        bf[1] = f1.v;

        if (q == 0) {
            // accH from bf = h_{t-1}: slot (t-1) semantics (R12-validated)
            pL[sl * 20 + (t - 1)]   = accH[1] + bpS;
            psiL[sl * 20 + (t - 1)] = accH[0] + bpsiS;
            if (t == 1) psiL[sl * 20] = accH[2] + bpsi0S;
        }
        x = x_next;
    }

    // ==== final heads on h_19 ====
    {
        f32x4 accH = __builtin_amdgcn_mfma_f32_16x16x32_f16(ldsb_(wb, ahd_off, 0), bf[0], zc, 0, 0, 0);
        accH = __builtin_amdgcn_mfma_f32_16x16x32_f16(ldsb_(wb, ahd_off, 64), bf[1], accH, 0, 0, 0);
        if (q == 0) {
            pL[sl * 20 + 19]   = accH[1] + bpS;
            psiL[sl * 20 + 19] = accH[0] + bpsiS;
        }
    }

    __syncthreads();

    // ==== epilogue: sigmoid + oxy, 256 threads over 64 sites, guarded ====
    const float wpo = W_p[HDIM];
    if (tid < 64 && base + tid < NSITES) out_psi0[base + tid] = sigmoidf_(psiL[tid * 20]);
#pragma unroll
    for (int r = 0; r < 5; ++r) {
        int i = r * 256 + tid;
        if (i < 64 * 19 && (size_t)base * 19 + i < (size_t)NSITES * 19) {
            int s2 = i / 19, c = i - s2 * 19;
            out_psi[(size_t)base * 19 + i] = sigmoidf_(psiL[s2 * 20 + c + 1]);
        }
    }
    const float4* oxy_b = (const float4*)(oxy + (size_t)base * 40);
    float4* outp_b = (float4*)(out_p + (size_t)base * 40);
    const int p4max = (NSITES * 40) / 4;
#pragma unroll
    for (int r = 0; r < 3; ++r) {
        int i4 = r * 256 + tid;
        if (i4 < 640 && blockIdx.x * 640 + i4 < p4max) {
            float4 ox = oxy_b[i4];
            float lg0 = pL[i4 * 2];
            float lg1 = pL[i4 * 2 + 1];
            float4 pv;
            pv.x = sigmoidf_(fmaf(wpo, ox.x, lg0));
            pv.y = sigmoidf_(fmaf(wpo, ox.y, lg0));
            pv.z = sigmoidf_(fmaf(wpo, ox.z, lg1));
            pv.w = sigmoidf_(fmaf(wpo, ox.w, lg1));
            outp_b[i4] = pv;
        }
    }
#undef OFFH
}

extern "C" void kernel_launch(void* const* d_in, const int* in_sizes, int n_in,
                              void* d_out, int out_size, void* d_ws, size_t ws_size,
                              hipStream_t stream) {
    const float* sxy0   = (const float*)d_in[0];
    const float* sxy    = (const float*)d_in[1];
    const float* oxy    = (const float*)d_in[2];
    const float* W_h0   = (const float*)d_in[3];
    const float* b_h0   = (const float*)d_in[4];
    const float* W_h1   = (const float*)d_in[5];
    const float* b_h1   = (const float*)d_in[6];
    const float* W_ih   = (const float*)d_in[7];
    const float* b_ih   = (const float*)d_in[8];
    const float* W_hh   = (const float*)d_in[9];
    const float* b_hh   = (const float*)d_in[10];
    const float* W_psi0 = (const float*)d_in[11];
    const float* b_psi0 = (const float*)d_in[12];
    const float* W_psi  = (const float*)d_in[13];
    const float* b_psi  = (const float*)d_in[14];
    const float* W_p    = (const float*)d_in[15];
    const float* b_p    = (const float*)d_in[16];

    float* out = (float*)d_out;

    dim3 block(256);
    dim3 grid((NSITES + 63) / 64);   // 1563 blocks, 4 waves x 16 sites each
    rnet_kernel<<<grid, block, 0, stream>>>(
        sxy0, sxy, oxy, W_h0, b_h0, W_h1, b_h1, W_ih, b_ih, W_hh, b_hh,
        W_psi0, b_psi0, W_psi, b_psi, W_p, b_p, out);
}

// Round 12
// 137.253 us; speedup vs baseline: 1.0427x; 1.0427x over previous
//
#include <hip/hip_runtime.h>
#include <math.h>

#define NSITES 100000
#define NYEARS 20
#define HDIM 64
#define WSTR 72   // LDS weight row stride (f16 elems); 144B, 16B-aligned

typedef _Float16 f16x8 __attribute__((ext_vector_type(8)));
typedef _Float16 hx2   __attribute__((ext_vector_type(2)));
typedef float f32x4 __attribute__((ext_vector_type(4)));

__device__ __forceinline__ float sigmoidf_(float x) { return 1.0f / (1.0f + __expf(-x)); }
// fast elu: __expf(x)-1 (error ~1e-7, far below tolerance; result is f16-truncated anyway)
__device__ __forceinline__ float eluf_(float x) { return x > 0.0f ? x : __expf(x) - 1.0f; }

__device__ __forceinline__ unsigned pack2h_(float a, float b) {
    union { _Float16 h; unsigned short u; } x, y;
    x.h = (_Float16)a; y.h = (_Float16)b;
    return ((unsigned)y.u << 16) | (unsigned)x.u;
}

// load 8 consecutive f32 (32B-aligned) -> f16x8
__device__ __forceinline__ f16x8 cvt8h_(const float* p) {
    float4 a = ((const float4*)p)[0];
    float4 b = ((const float4*)p)[1];
    f16x8 r;
    r[0] = (_Float16)a.x; r[1] = (_Float16)a.y; r[2] = (_Float16)a.z; r[3] = (_Float16)a.w;
    r[4] = (_Float16)b.x; r[5] = (_Float16)b.y; r[6] = (_Float16)b.z; r[7] = (_Float16)b.w;
    return r;
}

// read 8 f16 (16B) from LDS weight tile at (row, col off)
__device__ __forceinline__ f16x8 ldsfrag_(const unsigned short* b, int row, int off) {
    union { f16x8 v; uint4 u; } r;
    r.u = *(const uint4*)&b[row * WSTR + off];
    return r.v;
}

union FragU { hx2 h2[4]; f16x8 v; };

// R24 = R20 (best known, 44us/dispatch) with the kt0->kt1 MFMA dependency
// chain BROKEN. R23 post-mortem: 8 waves/SIMD ran clean (VGPR 32, no spill,
// Occ 2x) and dur WORSENED (52us, LDS bank conflicts 725K->4.1M from per-iter
// frag reads). Residency is conclusively falsified as the limiter: at 2x
// waves, issue utilization was unchanged (~44%). Per-iter wave latency
// (~1450cyc) vs issue work (~280cyc) says the loop is serial-DEPENDENCY-bound;
// the one unattacked dependency is the two serially-chained MFMA stages
// (kt1 accumulates onto kt0's D). This round: independent accumulators
//   acc0 = mfma(a_hh[mt][0], bf[0], biasD[mt])     (4 indep)
//   acc1 = mfma(a_hh[mt][1], bf[1], 0)             (4 indep)
//   accH0/accH1 likewise; merge with parallel v_add_f32 before the pack.
// All 10 MFMAs/iter are mutually independent -> critical path = 1 MFMA
// latency + add + pack (was 2 MFMA latencies + pack). Associativity-only
// change on the validated R8/R10 permuted-output-row recurrence.
// Structure otherwise R20: 4 waves x 16 sites, 64 sites/block, 1563 blocks,
// launch_bounds(256,2) (the only binding that never spilled), LDS 18432B =
// weight region overlaid by logits, x from global pipelined one round.
// Slot semantics: pL[sl*20+k]=p-logit(h_k) k=0..19;
//                 psiL[sl*20+k]=psi-logit(h_k) k=1..19, slot0=psi0-logit.
__global__ __launch_bounds__(256, 2)
void rnet_kernel(const float* __restrict__ sxy0,
                 const float* __restrict__ sxy,
                 const float* __restrict__ oxy,
                 const float* __restrict__ W_h0, const float* __restrict__ b_h0,
                 const float* __restrict__ W_h1, const float* __restrict__ b_h1,
                 const float* __restrict__ W_ih, const float* __restrict__ b_ih,
                 const float* __restrict__ W_hh, const float* __restrict__ b_hh,
                 const float* __restrict__ W_psi0, const float* __restrict__ b_psi0,
                 const float* __restrict__ W_psi, const float* __restrict__ b_psi,
                 const float* __restrict__ W_p, const float* __restrict__ b_p,
                 float* __restrict__ out)
{
    const int tid  = threadIdx.x;       // 0..255
    const int lane = tid & 63;
    const int wv   = tid >> 6;          // wave 0..3
    const int s = lane & 15;            // site within wave / A-row within tile
    const int q = lane >> 4;            // quad
    const int sq = s >> 2, sr = s & 3;
    const int base = blockIdx.x * 64;   // 1563 blocks; last block partial
    const int sl   = wv * 16 + s;       // site local 0..63
    const int site = base + sl;
    const int site_ld = site < NSITES ? site : NSITES - 1;   // clamped for loads

    // ==== LDS: single 18432B region = weights, later overlaid by logits ====
    __shared__ __align__(16) unsigned short wbuf[2 * 64 * WSTR]; // 18432 B
    unsigned short* const whh_l = wbuf;                 // f16 W_hh [64][WSTR]
    unsigned short* const wh1_l = wbuf + 64 * WSTR;     // f16 W_h1 [64][WSTR]
    float* const pL   = (float*)wbuf;                   // [64][20] p logits (overlay)
    float* const psiL = (float*)wbuf + 64 * 20;         // [64][20]; slot0 = psi0 logit

    float* __restrict__ out_psi0 = out;                 // [N]
    float* __restrict__ out_psi  = out + NSITES;        // [N,19]
    float* __restrict__ out_p    = out + 20 * NSITES;   // [N,20,2]

    // ==== stage weights (coalesced f32->f16) into LDS ====
    {
        const float4* whg = (const float4*)W_hh;
        const float4* w1g = (const float4*)W_h1;
#pragma unroll
        for (int j = 0; j < 4; ++j) {
            int e4 = j * 256 + tid;            // 0..1023 (1024 float4 = 64x64)
            int row = e4 >> 4, c4 = e4 & 15;
            float4 a = whg[e4];
            uint2 pa; pa.x = pack2h_(a.x, a.y); pa.y = pack2h_(a.z, a.w);
            *(uint2*)&whh_l[row * WSTR + c4 * 4] = pa;
            float4 b = w1g[e4];
            uint2 pb; pb.x = pack2h_(b.x, b.y); pb.y = pack2h_(b.z, b.w);
            *(uint2*)&wh1_l[row * WSTR + c4 * 4] = pb;
        }
    }
    __syncthreads();

    // ==== h0 stage: hs = elu(s0*W_h0+b_h0) in B layout; h0 via permuted W_h1 ====
    f16x8 bf[2];
    {
        const float s0v = sxy0[site_ld];
        f16x8 bf0[2];
#pragma unroll
        for (int kt = 0; kt < 2; ++kt) {
            const float* wp = W_h0 + kt * 32 + q * 8;
            const float* bp = b_h0 + kt * 32 + q * 8;
            float4 w0 = ((const float4*)wp)[0], w1 = ((const float4*)wp)[1];
            float4 c0 = ((const float4*)bp)[0], c1 = ((const float4*)bp)[1];
            float v[8];
            v[0] = eluf_(fmaf(s0v, w0.x, c0.x)); v[1] = eluf_(fmaf(s0v, w0.y, c0.y));
            v[2] = eluf_(fmaf(s0v, w0.z, c0.z)); v[3] = eluf_(fmaf(s0v, w0.w, c0.w));
            v[4] = eluf_(fmaf(s0v, w1.x, c1.x)); v[5] = eluf_(fmaf(s0v, w1.y, c1.y));
            v[6] = eluf_(fmaf(s0v, w1.z, c1.z)); v[7] = eluf_(fmaf(s0v, w1.w, c1.w));
#pragma unroll
            for (int j = 0; j < 8; ++j) bf0[kt][j] = (_Float16)v[j];
        }

        f32x4 acc[4];
#pragma unroll
        for (int mt = 0; mt < 4; ++mt) {
            const int dr = 32 * (mt >> 1) + 8 * q + 4 * (mt & 1);
            float4 b1 = *(const float4*)(b_h1 + dr);
            acc[mt][0] = b1.x; acc[mt][1] = b1.y; acc[mt][2] = b1.z; acc[mt][3] = b1.w;
        }
#pragma unroll
        for (int kt = 0; kt < 2; ++kt)
#pragma unroll
            for (int mt = 0; mt < 4; ++mt) {
                const int ar = 32 * (mt >> 1) + 8 * sq + 4 * (mt & 1) + sr;
                f16x8 a = ldsfrag_(wh1_l, ar, kt * 32 + q * 8);
                acc[mt] = __builtin_amdgcn_mfma_f32_16x16x32_f16(a, bf0[kt], acc[mt], 0, 0, 0);
            }
        FragU f0, f1;
#pragma unroll
        for (int mt = 0; mt < 4; ++mt) {
            hx2 plo; plo[0] = (_Float16)eluf_(acc[mt][0]); plo[1] = (_Float16)eluf_(acc[mt][1]);
            hx2 phi; phi[0] = (_Float16)eluf_(acc[mt][2]); phi[1] = (_Float16)eluf_(acc[mt][3]);
            if (mt < 2) { f0.h2[mt * 2] = plo; f0.h2[mt * 2 + 1] = phi; }
            else        { f1.h2[(mt - 2) * 2] = plo; f1.h2[(mt - 2) * 2 + 1] = phi; }
        }
        bf[0] = f0.v;
        bf[1] = f1.v;
    }

    // ==== persistent loop state: a_hh from LDS, small stuff direct ====
    f16x8 a_hh[4][2];
#pragma unroll
    for (int mt = 0; mt < 4; ++mt) {
        const int ar = 32 * (mt >> 1) + 8 * sq + 4 * (mt & 1) + sr;
#pragma unroll
        for (int kt = 0; kt < 2; ++kt)
            a_hh[mt][kt] = ldsfrag_(whh_l, ar, kt * 32 + q * 8);
    }

    // ALL cross-wave LDS weight reads done (wh1_l in h0, whh_l above).
    // Barrier before any wave overwrites the region with logits.
    __syncthreads();

    f16x8 a_head[2];
    {
        const float* hrow = (s == 1) ? W_p : ((s == 2) ? W_psi0 : W_psi);
#pragma unroll
        for (int kt = 0; kt < 2; ++kt) a_head[kt] = cvt8h_(hrow + kt * 32 + q * 8);
    }
    f32x4 biasD[4];
    hx2 wih2[4][2];
#pragma unroll
    for (int mt = 0; mt < 4; ++mt) {
        const int dr = 32 * (mt >> 1) + 8 * q + 4 * (mt & 1);
        float4 bi = *(const float4*)(b_ih + dr);
        float4 bh = *(const float4*)(b_hh + dr);
        float4 wi = *(const float4*)(W_ih + dr);
        biasD[mt][0] = bi.x + bh.x; biasD[mt][1] = bi.y + bh.y;
        biasD[mt][2] = bi.z + bh.z; biasD[mt][3] = bi.w + bh.w;
        wih2[mt][0][0] = (_Float16)wi.x; wih2[mt][0][1] = (_Float16)wi.y;
        wih2[mt][1][0] = (_Float16)wi.z; wih2[mt][1][1] = (_Float16)wi.w;
    }
    f32x4 headC;
    headC[0] = (q == 0) ? b_psi[0]  : 0.0f;
    headC[1] = (q == 0) ? b_p[0]    : 0.0f;
    headC[2] = (q == 0) ? b_psi0[0] : 0.0f;
    headC[3] = 0.0f;
    f32x4 zc; zc[0] = 0.0f; zc[1] = 0.0f; zc[2] = 0.0f; zc[3] = 0.0f;
    const hx2 z2 = (hx2)(_Float16)0.0f;
    const float* __restrict__ xs_g = sxy + (size_t)site_ld * 19;

    // ==== recurrence: ROLLED; kt0/kt1 MFMAs INDEPENDENT, merged in VALU ====
    float x = xs_g[0];                 // x for round t=1
#pragma unroll 1
    for (int t = 1; t < NYEARS; ++t) {
        float x_next = (t < NYEARS - 1) ? xs_g[t] : 0.0f;

        f32x4 acc0[4], acc1[4], accH0, accH1;
#pragma unroll
        for (int mt = 0; mt < 4; ++mt)
            acc0[mt] = __builtin_amdgcn_mfma_f32_16x16x32_f16(a_hh[mt][0], bf[0], biasD[mt], 0, 0, 0);
        accH0 = __builtin_amdgcn_mfma_f32_16x16x32_f16(a_head[0], bf[0], headC, 0, 0, 0);
#pragma unroll
        for (int mt = 0; mt < 4; ++mt)
            acc1[mt] = __builtin_amdgcn_mfma_f32_16x16x32_f16(a_hh[mt][1], bf[1], zc, 0, 0, 0);
        accH1 = __builtin_amdgcn_mfma_f32_16x16x32_f16(a_head[1], bf[1], zc, 0, 0, 0);

        // merge (parallel f32 adds) + packed-f16 relu update; result IS B-frag
        _Float16 xh = (_Float16)x;
        hx2 x2; x2[0] = xh; x2[1] = xh;
        FragU f0, f1;
#pragma unroll
        for (int mt = 0; mt < 4; ++mt) {
            f32x4 asum = acc0[mt] + acc1[mt];
            hx2 plo; plo[0] = (_Float16)asum[0]; plo[1] = (_Float16)asum[1];
            hx2 phi; phi[0] = (_Float16)asum[2]; phi[1] = (_Float16)asum[3];
            plo = __builtin_elementwise_max(plo + x2 * wih2[mt][0], z2);
            phi = __builtin_elementwise_max(phi + x2 * wih2[mt][1], z2);
            if (mt < 2) { f0.h2[mt * 2] = plo; f0.h2[mt * 2 + 1] = phi; }
            else        { f1.h2[(mt - 2) * 2] = plo; f1.h2[(mt - 2) * 2 + 1] = phi; }
        }
        bf[0] = f0.v;
        bf[1] = f1.v;

        if (q == 0) {
            // accH from bf = h_{t-1}: slot (t-1) semantics (R12-validated).
            float aH0 = accH0[0] + accH1[0];
            float aH1 = accH0[1] + accH1[1];
            pL[sl * 20 + (t - 1)]   = aH1;      // p-logit(h_{t-1}), slots 0..18
            psiL[sl * 20 + (t - 1)] = aH0;      // psi-logit(h_{t-1}); slot 0 dead
            if (t == 1) psiL[sl * 20] = accH0[2] + accH1[2]; // psi0-logit -> slot 0
        }
        x = x_next;
    }

    // ==== final heads on h_19 ====
    {
        f32x4 accH = __builtin_amdgcn_mfma_f32_16x16x32_f16(a_head[0], bf[0], headC, 0, 0, 0);
        accH = __builtin_amdgcn_mfma_f32_16x16x32_f16(a_head[1], bf[1], accH, 0, 0, 0);
        if (q == 0) {
            pL[sl * 20 + 19]   = accH[1];   // p-logit(h_19)
            psiL[sl * 20 + 19] = accH[0];   // psi-logit(h_19)
        }
    }

    __syncthreads();

    // ==== epilogue: sigmoid + oxy, 256 threads over 64 sites, guarded ====
    const float wpo = W_p[HDIM];
    if (tid < 64 && base + tid < NSITES) out_psi0[base + tid] = sigmoidf_(psiL[tid * 20]);
    // psi: 64*19 = 1216; out flat i = sl*19 + c <- psiL[sl*20 + c+1]
#pragma unroll
    for (int r = 0; r < 5; ++r) {
        int i = r * 256 + tid;
        if (i < 64 * 19 && (size_t)base * 19 + i < (size_t)NSITES * 19) {
            int s2 = i / 19, c = i - s2 * 19;
            out_psi[(size_t)base * 19 + i] = sigmoidf_(psiL[s2 * 20 + c + 1]);
        }
    }
    // p: 64*40 = 2560 floats = 640 float4; float4 idx i4 -> logits pL[i4*2..+1]
    const float4* oxy_b = (const float4*)(oxy + (size_t)base * 40);
    float4* outp_b = (float4*)(out_p + (size_t)base * 40);
    const int p4max = (NSITES * 40) / 4;   // global float4 bound
#pragma unroll
    for (int r = 0; r < 3; ++r) {
        int i4 = r * 256 + tid;
        if (i4 < 640 && blockIdx.x * 640 + i4 < p4max) {
            float4 ox = oxy_b[i4];
            float lg0 = pL[i4 * 2];
            float lg1 = pL[i4 * 2 + 1];
            float4 pv;
            pv.x = sigmoidf_(fmaf(wpo, ox.x, lg0));
            pv.y = sigmoidf_(fmaf(wpo, ox.y, lg0));
            pv.z = sigmoidf_(fmaf(wpo, ox.z, lg1));
            pv.w = sigmoidf_(fmaf(wpo, ox.w, lg1));
            outp_b[i4] = pv;
        }
    }
}

extern "C" void kernel_launch(void* const* d_in, const int* in_sizes, int n_in,
                              void* d_out, int out_size, void* d_ws, size_t ws_size,
                              hipStream_t stream) {
    const float* sxy0   = (const float*)d_in[0];
    const float* sxy    = (const float*)d_in[1];
    const float* oxy    = (const float*)d_in[2];
    const float* W_h0   = (const float*)d_in[3];
    const float* b_h0   = (const float*)d_in[4];
    const float* W_h1   = (const float*)d_in[5];
    const float* b_h1   = (const float*)d_in[6];
    const float* W_ih   = (const float*)d_in[7];
    const float* b_ih   = (const float*)d_in[8];
    const float* W_hh   = (const float*)d_in[9];
    const float* b_hh   = (const float*)d_in[10];
    const float* W_psi0 = (const float*)d_in[11];
    const float* b_psi0 = (const float*)d_in[12];
    const float* W_psi  = (const float*)d_in[13];
    const float* b_psi  = (const float*)d_in[14];
    const float* W_p    = (const float*)d_in[15];
    const float* b_p    = (const float*)d_in[16];

    float* out = (float*)d_out;

    dim3 block(256);
    dim3 grid((NSITES + 63) / 64);   // 1563 blocks, 4 waves x 16 sites each
    rnet_kernel<<<grid, block, 0, stream>>>(
        sxy0, sxy, oxy, W_h0, b_h0, W_h1, b_h1, W_ih, b_ih, W_hh, b_hh,
        W_psi0, b_psi0, W_psi, b_psi, W_p, b_p, out);
}